// Round 3
// baseline (483.707 us; speedup 1.0000x reference)
//
#include <hip/hip_runtime.h>

// -------------------- helpers --------------------
static __device__ __forceinline__ float4 ld4(const float* p) { return *(const float4*)p; }
static __device__ __forceinline__ float b2f(unsigned short u) {
    return __uint_as_float((unsigned)u << 16);
}
static __device__ __forceinline__ float b2f_lo(unsigned u) { return __uint_as_float(u << 16); }
static __device__ __forceinline__ float b2f_hi(unsigned u) { return __uint_as_float(u & 0xFFFF0000u); }
static __device__ __forceinline__ unsigned short f2b(float f) {   // round-to-nearest-even
    unsigned x = __float_as_uint(f);
    return (unsigned short)((x + 0x7FFFu + ((x >> 16) & 1u)) >> 16);
}
static __device__ __forceinline__ unsigned pk2(float lo, float hi) {
    return (unsigned)f2b(lo) | ((unsigned)f2b(hi) << 16);
}

#define NPB 256              // nodes per bin (pow2: ld = d & 255, bin = d >> 8)
#define CAPE 5120            // per-bin edge capacity (mean 4092, sigma 64 -> 16 sigma slack)

// math: out[d] = dinv[d]*( g[d] + sum_e ew_e * g[src_e] ) + bias,  g = dinv (.) h
// CSR stores (src, raw ew); dinv folded into gemm2 epilogue and csr_build's h-scale pass.

// ==================== fused kernel 1: gemm1 (x@W1 -> h, row/thread) + edge binning ==========
// blocks [0, gb): one row per thread; acc[64] in VGPRs; W via wave-uniform s_load (no LDS).
// blocks [gb, gb+bb): bin 4096 edges by dst>>8 into ebuf segments (packed u64).
// packed entry: [ew:32][ld:8][src:17]
__global__ __launch_bounds__(256) void k_fused1(const float* __restrict__ A,
                                                const float* __restrict__ W0,
                                                unsigned short* __restrict__ gout,
                                                const int* __restrict__ src,
                                                const int* __restrict__ dst,
                                                const float* __restrict__ ew,
                                                int* __restrict__ bin_cnt,
                                                unsigned long long* __restrict__ ebuf,
                                                int n, int E, int gb, int NB) {
    __shared__ int hist[512];
    __shared__ int hbase[512];
    int tid = threadIdx.x;

    if ((int)blockIdx.x < gb) {
        // ---------------- gemm1 path: h = x @ W1 (fp32 acc, bf16 store; dinv applied later)
        int row = blockIdx.x * 256 + tid;
        if (row >= n) return;
        const float* xr = A + (size_t)row * 128;
        float acc[64];
        #pragma unroll
        for (int c = 0; c < 64; c++) acc[c] = 0.f;
        // chunk 0 preload (each lane's 64B chunk = one cache line)
        float4 xa0 = ld4(xr), xa1 = ld4(xr + 4), xa2 = ld4(xr + 8), xa3 = ld4(xr + 12);
        for (int ch = 0; ch < 8; ch++) {
            float4 xb0, xb1, xb2, xb3;
            bool more = (ch < 7);
            if (more) {
                const float* nx = xr + ch * 16 + 16;
                xb0 = ld4(nx); xb1 = ld4(nx + 4); xb2 = ld4(nx + 8); xb3 = ld4(nx + 12);
            }
            float xs[16];
            xs[0] = xa0.x; xs[1] = xa0.y; xs[2] = xa0.z; xs[3] = xa0.w;
            xs[4] = xa1.x; xs[5] = xa1.y; xs[6] = xa1.z; xs[7] = xa1.w;
            xs[8] = xa2.x; xs[9] = xa2.y; xs[10] = xa2.z; xs[11] = xa2.w;
            xs[12] = xa3.x; xs[13] = xa3.y; xs[14] = xa3.z; xs[15] = xa3.w;
            #pragma unroll
            for (int kk = 0; kk < 16; kk++) {
                float xk = xs[kk];
                const float* wr = W0 + (size_t)(ch * 16 + kk) * 64;   // wave-uniform -> s_load
                #pragma unroll
                for (int c = 0; c < 64; c++)
                    acc[c] = fmaf(xk, wr[c], acc[c]);
            }
            if (more) { xa0 = xb0; xa1 = xb1; xa2 = xb2; xa3 = xb3; }
        }
        unsigned short* op = gout + (size_t)row * 64;
        #pragma unroll
        for (int c = 0; c < 64; c += 8) {
            uint4 u = make_uint4(pk2(acc[c], acc[c + 1]), pk2(acc[c + 2], acc[c + 3]),
                                 pk2(acc[c + 4], acc[c + 5]), pk2(acc[c + 6], acc[c + 7]));
            *(uint4*)(op + c) = u;
        }
    } else {
        // ---------------- bin path: 4096 edges
        for (int j = tid; j < NB; j += 256) hist[j] = 0;
        __syncthreads();
        int e0 = ((int)blockIdx.x - gb) * 4096;
        unsigned long long pk[16]; int bb[16]; int loc[16];
        #pragma unroll
        for (int j = 0; j < 16; j++) {
            int e = e0 + j * 256 + tid;
            if (e < E) {
                int s = src[e];
                int d = dst[e];
                float w = ew[e];
                bb[j] = d >> 8;
                pk[j] = ((unsigned long long)__float_as_uint(w) << 32) |
                        (unsigned)((d & (NPB - 1)) << 17) | (unsigned)s;
                loc[j] = atomicAdd(&hist[bb[j]], 1);
            } else bb[j] = -1;
        }
        __syncthreads();
        for (int j = tid; j < NB; j += 256) hbase[j] = atomicAdd(&bin_cnt[j], hist[j]);
        __syncthreads();
        #pragma unroll
        for (int j = 0; j < 16; j++) {
            if (bb[j] >= 0)
                ebuf[(size_t)bb[j] * CAPE + hbase[bb[j]] + loc[j]] = pk[j];
        }
    }
}

// ==================== pass 2: per-bin LDS-resident count+scan+scatter + h-scale ============
__global__ __launch_bounds__(512) void k_csr_build(const unsigned long long* __restrict__ ebuf,
                                                   const int* __restrict__ bin_cnt,
                                                   int2* __restrict__ rowcnt,
                                                   float* __restrict__ dinv,
                                                   unsigned long long* __restrict__ csr,
                                                   unsigned short* __restrict__ h0,
                                                   int n) {
    __shared__ unsigned long long eL[CAPE];   // 40 KB
    __shared__ unsigned cntL[NPB];
    __shared__ unsigned ewsL[NPB];
    __shared__ unsigned fillL[NPB];
    __shared__ int scanL[512];
    __shared__ int rowL[NPB];
    __shared__ float dinvL[NPB];
    __shared__ int binbase_s;
    int b = blockIdx.x;
    int tid = threadIdx.x;
    if (tid < NPB) { cntL[tid] = 0; ewsL[tid] = 0; fillL[tid] = 0; }
    scanL[tid] = (tid < b) ? bin_cnt[tid] : 0;
    __syncthreads();
    int m = bin_cnt[b];
    const unsigned long long* eb = ebuf + (size_t)b * CAPE;
    for (int i = tid; i < m; i += 512) {
        unsigned long long pk = eb[i];
        eL[i] = pk;
        int ld = (int)((pk >> 17) & (NPB - 1));
        float w = __uint_as_float((unsigned)(pk >> 32));
        atomicAdd(&cntL[ld], 1u);
        atomicAdd(&ewsL[ld], (unsigned)(w * 16777216.0f));   // 2^24 fixed point
    }
    __syncthreads();
    // bin base = sum of bin_cnt[0..b)
    #pragma unroll
    for (int off = 256; off > 0; off >>= 1) {
        if (tid < off) scanL[tid] += scanL[tid + off];
        __syncthreads();
    }
    if (tid == 0) binbase_s = scanL[0];
    __syncthreads();
    // exclusive prefix over cntL (512-wide, entries >= NPB are zero)
    int v = (tid < NPB) ? (int)cntL[tid] : 0;
    scanL[tid] = v;
    __syncthreads();
    #pragma unroll
    for (int off = 1; off < 512; off <<= 1) {
        int t = (tid >= off) ? scanL[tid - off] : 0;
        __syncthreads();
        scanL[tid] += t;
        __syncthreads();
    }
    if (tid < NPB) {
        int rp = binbase_s + scanL[tid] - v;
        rowL[tid] = rp;
        float dv = rsqrtf(1.0f + (float)ewsL[tid] * (1.0f / 16777216.0f));
        dinvL[tid] = dv;
        int node = b * NPB + tid;
        if (node < n) {
            rowcnt[node] = make_int2(rp, v);
            dinv[node] = dv;
        }
    }
    __syncthreads();
    // scatter from LDS; csr entry = (src, raw ew)
    for (int i = tid; i < m; i += 512) {
        unsigned long long pk = eL[i];
        int s = (int)(pk & 0x1FFFF);
        int ld = (int)((pk >> 17) & (NPB - 1));
        int pos = rowL[ld] + (int)atomicAdd(&fillL[ld], 1u);
        csr[pos] = (unsigned long long)(unsigned)s | (pk & 0xFFFFFFFF00000000ull);
    }
    // fused h-scale: g = dinv (.) h for this block's 256 nodes (replaces k_scale kernel)
    for (int idx = tid; idx < NPB * 8; idx += 512) {
        int ln = idx >> 3;
        int node = b * NPB + ln;
        if (node < n) {
            float sc = dinvL[ln];
            unsigned short* hp = h0 + (size_t)node * 64 + (idx & 7) * 8;
            uint4 u = *(uint4*)hp;
            u.x = pk2(b2f_lo(u.x) * sc, b2f_hi(u.x) * sc);
            u.y = pk2(b2f_lo(u.y) * sc, b2f_hi(u.y) * sc);
            u.z = pk2(b2f_lo(u.z) * sc, b2f_hi(u.z) * sc);
            u.w = pk2(b2f_lo(u.w) * sc, b2f_hi(u.w) * sc);
            *(uint4*)hp = u;
        }
    }
}

// ==================== layer-2 GEMM: g2 = dinv (.) (h @ [Wmu|Wlv]), row per thread ===========
__global__ __launch_bounds__(256) void k_gemm2(const unsigned short* __restrict__ h,
                                               const float* __restrict__ Wmu,
                                               const float* __restrict__ Wlv,
                                               const float* __restrict__ dinv,
                                               unsigned short* __restrict__ out, int n) {
    int row = blockIdx.x * 256 + threadIdx.x;
    if (row >= n) return;
    const unsigned short* xr = h + (size_t)row * 64;
    float acc[64];
    #pragma unroll
    for (int c = 0; c < 64; c++) acc[c] = 0.f;
    uint4 xa0 = *(const uint4*)xr;          // k 0..7
    uint4 xa1 = *(const uint4*)(xr + 8);    // k 8..15
    for (int ch = 0; ch < 4; ch++) {        // 16 k per chunk
        uint4 xb0, xb1;
        bool more = (ch < 3);
        if (more) {
            const unsigned short* nx = xr + ch * 16 + 16;
            xb0 = *(const uint4*)nx;
            xb1 = *(const uint4*)(nx + 8);
        }
        float xs[16];
        xs[0] = b2f_lo(xa0.x); xs[1] = b2f_hi(xa0.x);
        xs[2] = b2f_lo(xa0.y); xs[3] = b2f_hi(xa0.y);
        xs[4] = b2f_lo(xa0.z); xs[5] = b2f_hi(xa0.z);
        xs[6] = b2f_lo(xa0.w); xs[7] = b2f_hi(xa0.w);
        xs[8] = b2f_lo(xa1.x); xs[9] = b2f_hi(xa1.x);
        xs[10] = b2f_lo(xa1.y); xs[11] = b2f_hi(xa1.y);
        xs[12] = b2f_lo(xa1.z); xs[13] = b2f_hi(xa1.z);
        xs[14] = b2f_lo(xa1.w); xs[15] = b2f_hi(xa1.w);
        #pragma unroll
        for (int kk = 0; kk < 16; kk++) {
            float xk = xs[kk];
            int k = ch * 16 + kk;
            const float* wmu = Wmu + (size_t)k * 32;   // wave-uniform -> s_load
            const float* wlv = Wlv + (size_t)k * 32;
            #pragma unroll
            for (int c = 0; c < 32; c++)
                acc[c] = fmaf(xk, wmu[c], acc[c]);
            #pragma unroll
            for (int c = 0; c < 32; c++)
                acc[32 + c] = fmaf(xk, wlv[c], acc[32 + c]);
        }
        if (more) { xa0 = xb0; xa1 = xb1; }
    }
    float di = dinv[row];
    unsigned short* op = out + (size_t)row * 64;
    #pragma unroll
    for (int c = 0; c < 64; c += 8) {
        uint4 u = make_uint4(pk2(acc[c] * di, acc[c + 1] * di),
                             pk2(acc[c + 2] * di, acc[c + 3] * di),
                             pk2(acc[c + 4] * di, acc[c + 5] * di),
                             pk2(acc[c + 6] * di, acc[c + 7] * di));
        *(uint4*)(op + c) = u;
    }
}

// -------------------- propagation: one wave per node, 8 edges per VMEM instruction ----------
// g is dinv-scaled; csr = (src, raw ew). out = dinv[d]*(g[d] + sum w*g[s]) + bias.
// Lane layout: q = lane>>3 (edge slot 0..7), t = lane&7 (channel octet 8t..8t+7, uint4 load).
// Straight-line 32-edge body: 4 csr loads + 4 gathers all in flight (branchless clamp,
// OOB slots read edge m-1 with weight 0 -> same cache line, negligible cost).
static __device__ __forceinline__ void acc8(float* a, uint4 r, float wt) {
    a[0] = fmaf(b2f_lo(r.x), wt, a[0]); a[1] = fmaf(b2f_hi(r.x), wt, a[1]);
    a[2] = fmaf(b2f_lo(r.y), wt, a[2]); a[3] = fmaf(b2f_hi(r.y), wt, a[3]);
    a[4] = fmaf(b2f_lo(r.z), wt, a[4]); a[5] = fmaf(b2f_hi(r.z), wt, a[5]);
    a[6] = fmaf(b2f_lo(r.w), wt, a[6]); a[7] = fmaf(b2f_hi(r.w), wt, a[7]);
}

template<bool RELU, bool SPLIT_OUT>
__global__ __launch_bounds__(256) void k_prop(const unsigned short* __restrict__ g,
                                              const int2* __restrict__ csr,
                                              const int2* __restrict__ rowcnt,
                                              const float* __restrict__ dinv,
                                              const float* __restrict__ bias0,
                                              const float* __restrict__ bias1,
                                              void* __restrict__ outv, int n) {
    int node = blockIdx.x * 4 + (threadIdx.x >> 6);
    if (node >= n) return;
    int lane = threadIdx.x & 63;
    int q = lane >> 3;          // edge slot 0..7
    int t = lane & 7;           // channel octet: channels 8t..8t+7
    // self row: independent of the csr chain -> issue first (coalesces to one line)
    uint4 sr = *(const uint4*)(g + (size_t)node * 64 + t * 8);
    int2 rc = rowcnt[node];
    const int2* ep = csr + rc.x;
    int m = rc.y;
    float a[8] = {};
    for (int e = 0; e < m; e += 32) {
        int e1 = e + q, e2 = e1 + 8, e3 = e1 + 16, e4 = e1 + 24;
        int i1 = min(e1, m - 1), i2 = min(e2, m - 1);
        int i3 = min(e3, m - 1), i4 = min(e4, m - 1);
        int2 p1 = ep[i1];
        int2 p2 = ep[i2];
        int2 p3 = ep[i3];
        int2 p4 = ep[i4];
        uint4 r1 = *(const uint4*)(g + (size_t)p1.x * 64 + t * 8);
        uint4 r2 = *(const uint4*)(g + (size_t)p2.x * 64 + t * 8);
        uint4 r3 = *(const uint4*)(g + (size_t)p3.x * 64 + t * 8);
        uint4 r4 = *(const uint4*)(g + (size_t)p4.x * 64 + t * 8);
        float w1 = (e1 < m) ? __int_as_float(p1.y) : 0.f;
        float w2 = (e2 < m) ? __int_as_float(p2.y) : 0.f;
        float w3 = (e3 < m) ? __int_as_float(p3.y) : 0.f;
        float w4 = (e4 < m) ? __int_as_float(p4.y) : 0.f;
        acc8(a, r1, w1);
        acc8(a, r2, w2);
        acc8(a, r3, w3);
        acc8(a, r4, w4);
    }
    #pragma unroll
    for (int i = 0; i < 8; i++) {
        a[i] += __shfl_xor(a[i], 8);
        a[i] += __shfl_xor(a[i], 16);
        a[i] += __shfl_xor(a[i], 32);
    }
    if (q != 0) return;
    // lanes 0..7: t = lane, channels 8t..8t+7
    a[0] += b2f_lo(sr.x); a[1] += b2f_hi(sr.x);
    a[2] += b2f_lo(sr.y); a[3] += b2f_hi(sr.y);
    a[4] += b2f_lo(sr.z); a[5] += b2f_hi(sr.z);
    a[6] += b2f_lo(sr.w); a[7] += b2f_hi(sr.w);
    float di = dinv[node];
    #pragma unroll
    for (int i = 0; i < 8; i++) a[i] *= di;
    if (!SPLIT_OUT) {
        float4 b0 = ld4(bias0 + t * 8);
        float4 b1 = ld4(bias0 + t * 8 + 4);
        a[0] += b0.x; a[1] += b0.y; a[2] += b0.z; a[3] += b0.w;
        a[4] += b1.x; a[5] += b1.y; a[6] += b1.z; a[7] += b1.w;
        if (RELU) {
            #pragma unroll
            for (int i = 0; i < 8; i++) a[i] = fmaxf(a[i], 0.f);
        }
        uint4 u = make_uint4(pk2(a[0], a[1]), pk2(a[2], a[3]),
                             pk2(a[4], a[5]), pk2(a[6], a[7]));
        *(uint4*)((unsigned short*)outv + (size_t)node * 64 + t * 8) = u;
    } else {
        float* out = (float*)outv;
        const float* bp = (t < 4) ? (bias0 + t * 8) : (bias1 + (t - 4) * 8);
        size_t base = (t < 4) ? ((size_t)node * 32 + t * 8)
                              : ((size_t)n * 32 + (size_t)node * 32 + (t - 4) * 8);
        float4 b0 = ld4(bp);
        float4 b1 = ld4(bp + 4);
        float4 v0 = make_float4(a[0] + b0.x, a[1] + b0.y, a[2] + b0.z, a[3] + b0.w);
        float4 v1 = make_float4(a[4] + b1.x, a[5] + b1.y, a[6] + b1.z, a[7] + b1.w);
        *(float4*)&out[base] = v0;
        *(float4*)&out[base + 4] = v1;
    }
}

// -------------------- launch --------------------
extern "C" void kernel_launch(void* const* d_in, const int* in_sizes, int n_in,
                              void* d_out, int out_size, void* d_ws, size_t ws_size,
                              hipStream_t stream) {
    const float* x   = (const float*)d_in[0];
    const int*   ei  = (const int*)d_in[1];   // [2, E]
    const float* ew  = (const float*)d_in[2];
    const float* W1  = (const float*)d_in[3];
    const float* b1  = (const float*)d_in[4];
    const float* Wmu = (const float*)d_in[5];
    const float* bmu = (const float*)d_in[6];
    const float* Wlv = (const float*)d_in[7];
    const float* blv = (const float*)d_in[8];
    float* outp = (float*)d_out;

    const int n = in_sizes[0] / 128;
    const int E = in_sizes[2];
    const int* src = ei;
    const int* dst = ei + E;
    const int NB = (n + NPB - 1) / NPB;            // bins of 256 nodes (391)

    // workspace layout
    size_t o = 0;
    auto alloc = [&](size_t bytes) { void* p = (char*)d_ws + o; o += (bytes + 511) & ~(size_t)511; return p; };
    int*   bin_cnt  = (int*)alloc((size_t)NB * 4);                 // memset 0
    int2*  rowcnt   = (int2*)alloc((size_t)n * 8);
    float* dinv     = (float*)alloc((size_t)n * 4);
    unsigned long long* csr  = (unsigned long long*)alloc((size_t)E * 8);
    unsigned long long* ebuf = (unsigned long long*)alloc((size_t)NB * CAPE * 8);
    unsigned short* g0 = (unsigned short*)alloc((size_t)n * 64 * 2);   // bf16
    unsigned short* h  = (unsigned short*)alloc((size_t)n * 64 * 2);   // bf16
    unsigned short* g2 = g0;   // gemm2 output reuses g0 (dead after prop1)

    const int gb = (n + 255) / 256;                // gemm blocks (391), one row per thread
    const int bb = (E + 4095) / 4096;              // bin blocks (391)

    hipMemsetAsync(bin_cnt, 0, (size_t)NB * 4, stream);
    k_fused1<<<gb + bb, 256, 0, stream>>>(x, W1, g0, src, dst, ew,
                                          bin_cnt, ebuf, n, E, gb, NB);
    k_csr_build<<<NB, 512, 0, stream>>>(ebuf, bin_cnt, rowcnt, dinv, csr, g0, n);
    k_prop<true, false><<<(n + 3) / 4, 256, 0, stream>>>(g0, (const int2*)csr, rowcnt, dinv,
                                                         b1, nullptr, h, n);
    k_gemm2<<<gb, 256, 0, stream>>>(h, Wmu, Wlv, dinv, g2, n);
    k_prop<false, true><<<(n + 3) / 4, 256, 0, stream>>>(g2, (const int2*)csr, rowcnt, dinv,
                                                         bmu, blv, outp, n);
}

// Round 4
// 277.722 us; speedup vs baseline: 1.7417x; 1.7417x over previous
//
#include <hip/hip_runtime.h>

// -------------------- helpers --------------------
static __device__ __forceinline__ float4 ld4(const float* p) { return *(const float4*)p; }
static __device__ __forceinline__ float b2f(unsigned short u) {
    return __uint_as_float((unsigned)u << 16);
}
static __device__ __forceinline__ float b2f_lo(unsigned u) { return __uint_as_float(u << 16); }
static __device__ __forceinline__ float b2f_hi(unsigned u) { return __uint_as_float(u & 0xFFFF0000u); }
static __device__ __forceinline__ unsigned short f2b(float f) {   // round-to-nearest-even
    unsigned x = __float_as_uint(f);
    return (unsigned short)((x + 0x7FFFu + ((x >> 16) & 1u)) >> 16);
}
static __device__ __forceinline__ unsigned pk2(float lo, float hi) {
    return (unsigned)f2b(lo) | ((unsigned)f2b(hi) << 16);
}

#define NPB 256              // nodes per bin (pow2: ld = d & 255, bin = d >> 8)
#define CAPE 5120            // per-bin edge capacity (mean 4092, sigma 64 -> 16 sigma slack)

// math: out[d] = dinv[d]*( g[d] + sum_e ew_e * g[src_e] ) + bias,  g = dinv (.) h
// CSR stores (src, raw ew); dinv folded into gemm2 epilogue and csr_build's h-scale pass.

// GEMM tile scheme (both layers): 128 rows x 64 cols per block, 256 threads,
// 8 rows x 4 cols per thread. Xs swizzled: float-quad at column (kc ^ 4*(row>>3))
// so the 4 row-groups of a wave read disjoint bank-quads (kills the 4-way conflict).
// Per kk-quad per lane: 8 X + 4 W ds_read_b128 = 1.5 B/FMA -> VALU-bound.

// ==================== fused kernel 1: gemm1 (x@W1 -> h) + edge binning ====================
// blocks [0, gb): gemm tile as above, K=128 in two 64-chunks.
// blocks [gb, gb+bb): bin 4096 edges by dst>>8 into ebuf segments (packed u64).
// packed entry: [ew:32][ld:8][src:17]
__global__ __launch_bounds__(256) void k_fused1(const float* __restrict__ A,
                                                const float* __restrict__ W0,
                                                unsigned short* __restrict__ gout,
                                                const int* __restrict__ src,
                                                const int* __restrict__ dst,
                                                const float* __restrict__ ew,
                                                int* __restrict__ bin_cnt,
                                                unsigned long long* __restrict__ ebuf,
                                                int n, int E, int gb, int NB) {
    __shared__ float Ws[64 * 64];     // 16 KB
    __shared__ float Xs[128 * 64];    // 32 KB
    __shared__ int hist[512];
    __shared__ int hbase[512];
    int tid = threadIdx.x;

    if ((int)blockIdx.x < gb) {
        // ---------------- gemm1 path: h = x @ W1 (fp32 acc, bf16 store; dinv applied later)
        int row0 = blockIdx.x * 128;
        int c0 = (tid & 15) * 4;
        int rb = tid >> 4;            // 0..15
        int r0 = rb * 8;
        int swz = rb * 4;             // XOR offset (floats) shared by this thread's 8 rows
        float4 acc[8] = {};
        #pragma unroll
        for (int p = 0; p < 2; p++) {
            // stage W chunk: rows p*64..p*64+63 (4096 floats, linear)
            for (int j = tid; j < 1024; j += 256)
                *(float4*)&Ws[j * 4] = ld4(W0 + p * 4096 + j * 4);
            // stage X chunk: 128 rows x 64 k, swizzled
            for (int j = tid; j < 2048; j += 256) {
                int r = j >> 4, kc = (j & 15) * 4;
                int grow = row0 + r;
                float4 v = make_float4(0.f, 0.f, 0.f, 0.f);
                if (grow < n) v = ld4(A + (size_t)grow * 128 + p * 64 + kc);
                int sw = ((r >> 3) & 15) * 4;
                *(float4*)&Xs[r * 64 + (kc ^ sw)] = v;
            }
            __syncthreads();
            #pragma unroll 2
            for (int kk = 0; kk < 64; kk += 4) {
                float4 w0 = ld4(&Ws[(kk + 0) * 64 + c0]);
                float4 w1 = ld4(&Ws[(kk + 1) * 64 + c0]);
                float4 w2 = ld4(&Ws[(kk + 2) * 64 + c0]);
                float4 w3 = ld4(&Ws[(kk + 3) * 64 + c0]);
                #pragma unroll
                for (int i = 0; i < 8; i++) {
                    float4 a = ld4(&Xs[(r0 + i) * 64 + (kk ^ swz)]);
                    acc[i].x = fmaf(a.x, w0.x, fmaf(a.y, w1.x, fmaf(a.z, w2.x, fmaf(a.w, w3.x, acc[i].x))));
                    acc[i].y = fmaf(a.x, w0.y, fmaf(a.y, w1.y, fmaf(a.z, w2.y, fmaf(a.w, w3.y, acc[i].y))));
                    acc[i].z = fmaf(a.x, w0.z, fmaf(a.y, w1.z, fmaf(a.z, w2.z, fmaf(a.w, w3.z, acc[i].z))));
                    acc[i].w = fmaf(a.x, w0.w, fmaf(a.y, w1.w, fmaf(a.z, w2.w, fmaf(a.w, w3.w, acc[i].w))));
                }
            }
            __syncthreads();
        }
        #pragma unroll
        for (int i = 0; i < 8; i++) {
            int grow = row0 + r0 + i;
            if (grow < n) {
                ushort4 u = make_ushort4(f2b(acc[i].x), f2b(acc[i].y), f2b(acc[i].z), f2b(acc[i].w));
                *(ushort4*)&gout[(size_t)grow * 64 + c0] = u;
            }
        }
    } else {
        // ---------------- bin path: 4096 edges
        for (int j = tid; j < NB; j += 256) hist[j] = 0;
        __syncthreads();
        int e0 = ((int)blockIdx.x - gb) * 4096;
        unsigned long long pk[16]; int bb[16]; int loc[16];
        #pragma unroll
        for (int j = 0; j < 16; j++) {
            int e = e0 + j * 256 + tid;
            if (e < E) {
                int s = src[e];
                int d = dst[e];
                float w = ew[e];
                bb[j] = d >> 8;
                pk[j] = ((unsigned long long)__float_as_uint(w) << 32) |
                        (unsigned)((d & (NPB - 1)) << 17) | (unsigned)s;
                loc[j] = atomicAdd(&hist[bb[j]], 1);
            } else bb[j] = -1;
        }
        __syncthreads();
        for (int j = tid; j < NB; j += 256) hbase[j] = atomicAdd(&bin_cnt[j], hist[j]);
        __syncthreads();
        #pragma unroll
        for (int j = 0; j < 16; j++) {
            if (bb[j] >= 0)
                ebuf[(size_t)bb[j] * CAPE + hbase[bb[j]] + loc[j]] = pk[j];
        }
    }
}

// ==================== pass 2: per-bin LDS-resident count+scan+scatter + h-scale ============
__global__ __launch_bounds__(512) void k_csr_build(const unsigned long long* __restrict__ ebuf,
                                                   const int* __restrict__ bin_cnt,
                                                   int2* __restrict__ rowcnt,
                                                   float* __restrict__ dinv,
                                                   unsigned long long* __restrict__ csr,
                                                   unsigned short* __restrict__ h0,
                                                   int n) {
    __shared__ unsigned long long eL[CAPE];   // 40 KB
    __shared__ unsigned cntL[NPB];
    __shared__ unsigned ewsL[NPB];
    __shared__ unsigned fillL[NPB];
    __shared__ int scanL[512];
    __shared__ int rowL[NPB];
    __shared__ float dinvL[NPB];
    __shared__ int binbase_s;
    int b = blockIdx.x;
    int tid = threadIdx.x;
    if (tid < NPB) { cntL[tid] = 0; ewsL[tid] = 0; fillL[tid] = 0; }
    scanL[tid] = (tid < b) ? bin_cnt[tid] : 0;
    __syncthreads();
    int m = bin_cnt[b];
    const unsigned long long* eb = ebuf + (size_t)b * CAPE;
    for (int i = tid; i < m; i += 512) {
        unsigned long long pk = eb[i];
        eL[i] = pk;
        int ld = (int)((pk >> 17) & (NPB - 1));
        float w = __uint_as_float((unsigned)(pk >> 32));
        atomicAdd(&cntL[ld], 1u);
        atomicAdd(&ewsL[ld], (unsigned)(w * 16777216.0f));   // 2^24 fixed point
    }
    __syncthreads();
    // bin base = sum of bin_cnt[0..b)
    #pragma unroll
    for (int off = 256; off > 0; off >>= 1) {
        if (tid < off) scanL[tid] += scanL[tid + off];
        __syncthreads();
    }
    if (tid == 0) binbase_s = scanL[0];
    __syncthreads();
    // exclusive prefix over cntL (512-wide, entries >= NPB are zero)
    int v = (tid < NPB) ? (int)cntL[tid] : 0;
    scanL[tid] = v;
    __syncthreads();
    #pragma unroll
    for (int off = 1; off < 512; off <<= 1) {
        int t = (tid >= off) ? scanL[tid - off] : 0;
        __syncthreads();
        scanL[tid] += t;
        __syncthreads();
    }
    if (tid < NPB) {
        int rp = binbase_s + scanL[tid] - v;
        rowL[tid] = rp;
        float dv = rsqrtf(1.0f + (float)ewsL[tid] * (1.0f / 16777216.0f));
        dinvL[tid] = dv;
        int node = b * NPB + tid;
        if (node < n) {
            rowcnt[node] = make_int2(rp, v);
            dinv[node] = dv;
        }
    }
    __syncthreads();
    // scatter from LDS; csr entry = (src, raw ew)
    for (int i = tid; i < m; i += 512) {
        unsigned long long pk = eL[i];
        int s = (int)(pk & 0x1FFFF);
        int ld = (int)((pk >> 17) & (NPB - 1));
        int pos = rowL[ld] + (int)atomicAdd(&fillL[ld], 1u);
        csr[pos] = (unsigned long long)(unsigned)s | (pk & 0xFFFFFFFF00000000ull);
    }
    // fused h-scale: g = dinv (.) h for this block's 256 nodes (replaces k_scale kernel)
    for (int idx = tid; idx < NPB * 8; idx += 512) {
        int ln = idx >> 3;
        int node = b * NPB + ln;
        if (node < n) {
            float sc = dinvL[ln];
            unsigned short* hp = h0 + (size_t)node * 64 + (idx & 7) * 8;
            uint4 u = *(uint4*)hp;
            u.x = pk2(b2f_lo(u.x) * sc, b2f_hi(u.x) * sc);
            u.y = pk2(b2f_lo(u.y) * sc, b2f_hi(u.y) * sc);
            u.z = pk2(b2f_lo(u.z) * sc, b2f_hi(u.z) * sc);
            u.w = pk2(b2f_lo(u.w) * sc, b2f_hi(u.w) * sc);
            *(uint4*)hp = u;
        }
    }
}

// ==================== layer-2 GEMM: g2 = dinv (.) (h @ [Wmu|Wlv]) ===========================
// Same 128x64 tile / 8x4-per-thread / swizzled-Xs scheme; K=64 single chunk; bf16 A.
__global__ __launch_bounds__(256) void k_gemm2(const unsigned short* __restrict__ h,
                                               const float* __restrict__ Wmu,
                                               const float* __restrict__ Wlv,
                                               const float* __restrict__ dinv,
                                               unsigned short* __restrict__ out, int n) {
    __shared__ float Ws[64 * 64];     // 16 KB
    __shared__ float Xs[128 * 64];    // 32 KB
    int tid = threadIdx.x;
    int row0 = blockIdx.x * 128;
    // stage W: cols 0-31 = Wmu, 32-63 = Wlv
    for (int j = tid; j < 1024; j += 256) {
        int k = (j * 4) >> 6;
        int c = (j * 4) & 63;
        float4 v = (c < 32) ? ld4(Wmu + k * 32 + c) : ld4(Wlv + k * 32 + (c - 32));
        *(float4*)&Ws[j * 4] = v;
    }
    // stage X: 128 rows x 64 k (bf16 -> fp32), swizzled
    for (int j = tid; j < 1024; j += 256) {
        int r = j >> 3, ko = (j & 7) * 8;
        int grow = row0 + r;
        uint4 u = make_uint4(0u, 0u, 0u, 0u);
        if (grow < n) u = *(const uint4*)(h + (size_t)grow * 64 + ko);
        int sw = ((r >> 3) & 15) * 4;
        float4 v0 = make_float4(b2f_lo(u.x), b2f_hi(u.x), b2f_lo(u.y), b2f_hi(u.y));
        float4 v1 = make_float4(b2f_lo(u.z), b2f_hi(u.z), b2f_lo(u.w), b2f_hi(u.w));
        *(float4*)&Xs[r * 64 + (ko ^ sw)] = v0;
        *(float4*)&Xs[r * 64 + ((ko + 4) ^ sw)] = v1;
    }
    __syncthreads();

    int c0 = (tid & 15) * 4;
    int rb = tid >> 4;
    int r0 = rb * 8;
    int swz = rb * 4;
    float4 acc[8] = {};
    #pragma unroll 2
    for (int kk = 0; kk < 64; kk += 4) {
        float4 w0 = ld4(&Ws[(kk + 0) * 64 + c0]);
        float4 w1 = ld4(&Ws[(kk + 1) * 64 + c0]);
        float4 w2 = ld4(&Ws[(kk + 2) * 64 + c0]);
        float4 w3 = ld4(&Ws[(kk + 3) * 64 + c0]);
        #pragma unroll
        for (int i = 0; i < 8; i++) {
            float4 a = ld4(&Xs[(r0 + i) * 64 + (kk ^ swz)]);
            acc[i].x = fmaf(a.x, w0.x, fmaf(a.y, w1.x, fmaf(a.z, w2.x, fmaf(a.w, w3.x, acc[i].x))));
            acc[i].y = fmaf(a.x, w0.y, fmaf(a.y, w1.y, fmaf(a.z, w2.y, fmaf(a.w, w3.y, acc[i].y))));
            acc[i].z = fmaf(a.x, w0.z, fmaf(a.y, w1.z, fmaf(a.z, w2.z, fmaf(a.w, w3.z, acc[i].z))));
            acc[i].w = fmaf(a.x, w0.w, fmaf(a.y, w1.w, fmaf(a.z, w2.w, fmaf(a.w, w3.w, acc[i].w))));
        }
    }
    #pragma unroll
    for (int i = 0; i < 8; i++) {
        int grow = row0 + r0 + i;
        if (grow < n) {
            float sc = dinv[grow];
            ushort4 u = make_ushort4(f2b(acc[i].x * sc), f2b(acc[i].y * sc),
                                     f2b(acc[i].z * sc), f2b(acc[i].w * sc));
            *(ushort4*)&out[(size_t)grow * 64 + c0] = u;
        }
    }
}

// -------------------- propagation: one wave per node, 8 edges per VMEM instruction ----------
// g is dinv-scaled; csr = (src, raw ew). out = dinv[d]*(g[d] + sum w*g[s]) + bias.
// Lane layout: q = lane>>3 (edge slot 0..7), t = lane&7 (channel octet 8t..8t+7, uint4 load).
// Straight-line 32-edge body: 4 csr loads + 4 gathers all in flight (branchless clamp,
// OOB slots read edge m-1 with weight 0 -> same cache line, negligible cost).
static __device__ __forceinline__ void acc8(float* a, uint4 r, float wt) {
    a[0] = fmaf(b2f_lo(r.x), wt, a[0]); a[1] = fmaf(b2f_hi(r.x), wt, a[1]);
    a[2] = fmaf(b2f_lo(r.y), wt, a[2]); a[3] = fmaf(b2f_hi(r.y), wt, a[3]);
    a[4] = fmaf(b2f_lo(r.z), wt, a[4]); a[5] = fmaf(b2f_hi(r.z), wt, a[5]);
    a[6] = fmaf(b2f_lo(r.w), wt, a[6]); a[7] = fmaf(b2f_hi(r.w), wt, a[7]);
}

template<bool RELU, bool SPLIT_OUT>
__global__ __launch_bounds__(256) void k_prop(const unsigned short* __restrict__ g,
                                              const int2* __restrict__ csr,
                                              const int2* __restrict__ rowcnt,
                                              const float* __restrict__ dinv,
                                              const float* __restrict__ bias0,
                                              const float* __restrict__ bias1,
                                              void* __restrict__ outv, int n) {
    int node = blockIdx.x * 4 + (threadIdx.x >> 6);
    if (node >= n) return;
    int lane = threadIdx.x & 63;
    int q = lane >> 3;          // edge slot 0..7
    int t = lane & 7;           // channel octet: channels 8t..8t+7
    // self row: independent of the csr chain -> issue first (coalesces to one line)
    uint4 sr = *(const uint4*)(g + (size_t)node * 64 + t * 8);
    int2 rc = rowcnt[node];
    const int2* ep = csr + rc.x;
    int m = rc.y;
    float a[8] = {};
    for (int e = 0; e < m; e += 32) {
        int e1 = e + q, e2 = e1 + 8, e3 = e1 + 16, e4 = e1 + 24;
        int i1 = min(e1, m - 1), i2 = min(e2, m - 1);
        int i3 = min(e3, m - 1), i4 = min(e4, m - 1);
        int2 p1 = ep[i1];
        int2 p2 = ep[i2];
        int2 p3 = ep[i3];
        int2 p4 = ep[i4];
        uint4 r1 = *(const uint4*)(g + (size_t)p1.x * 64 + t * 8);
        uint4 r2 = *(const uint4*)(g + (size_t)p2.x * 64 + t * 8);
        uint4 r3 = *(const uint4*)(g + (size_t)p3.x * 64 + t * 8);
        uint4 r4 = *(const uint4*)(g + (size_t)p4.x * 64 + t * 8);
        float w1 = (e1 < m) ? __int_as_float(p1.y) : 0.f;
        float w2 = (e2 < m) ? __int_as_float(p2.y) : 0.f;
        float w3 = (e3 < m) ? __int_as_float(p3.y) : 0.f;
        float w4 = (e4 < m) ? __int_as_float(p4.y) : 0.f;
        acc8(a, r1, w1);
        acc8(a, r2, w2);
        acc8(a, r3, w3);
        acc8(a, r4, w4);
    }
    #pragma unroll
    for (int i = 0; i < 8; i++) {
        a[i] += __shfl_xor(a[i], 8);
        a[i] += __shfl_xor(a[i], 16);
        a[i] += __shfl_xor(a[i], 32);
    }
    if (q != 0) return;
    // lanes 0..7: t = lane, channels 8t..8t+7
    a[0] += b2f_lo(sr.x); a[1] += b2f_hi(sr.x);
    a[2] += b2f_lo(sr.y); a[3] += b2f_hi(sr.y);
    a[4] += b2f_lo(sr.z); a[5] += b2f_hi(sr.z);
    a[6] += b2f_lo(sr.w); a[7] += b2f_hi(sr.w);
    float di = dinv[node];
    #pragma unroll
    for (int i = 0; i < 8; i++) a[i] *= di;
    if (!SPLIT_OUT) {
        float4 b0 = ld4(bias0 + t * 8);
        float4 b1 = ld4(bias0 + t * 8 + 4);
        a[0] += b0.x; a[1] += b0.y; a[2] += b0.z; a[3] += b0.w;
        a[4] += b1.x; a[5] += b1.y; a[6] += b1.z; a[7] += b1.w;
        if (RELU) {
            #pragma unroll
            for (int i = 0; i < 8; i++) a[i] = fmaxf(a[i], 0.f);
        }
        uint4 u = make_uint4(pk2(a[0], a[1]), pk2(a[2], a[3]),
                             pk2(a[4], a[5]), pk2(a[6], a[7]));
        *(uint4*)((unsigned short*)outv + (size_t)node * 64 + t * 8) = u;
    } else {
        float* out = (float*)outv;
        const float* bp = (t < 4) ? (bias0 + t * 8) : (bias1 + (t - 4) * 8);
        size_t base = (t < 4) ? ((size_t)node * 32 + t * 8)
                              : ((size_t)n * 32 + (size_t)node * 32 + (t - 4) * 8);
        float4 b0 = ld4(bp);
        float4 b1 = ld4(bp + 4);
        float4 v0 = make_float4(a[0] + b0.x, a[1] + b0.y, a[2] + b0.z, a[3] + b0.w);
        float4 v1 = make_float4(a[4] + b1.x, a[5] + b1.y, a[6] + b1.z, a[7] + b1.w);
        *(float4*)&out[base] = v0;
        *(float4*)&out[base + 4] = v1;
    }
}

// -------------------- launch --------------------
extern "C" void kernel_launch(void* const* d_in, const int* in_sizes, int n_in,
                              void* d_out, int out_size, void* d_ws, size_t ws_size,
                              hipStream_t stream) {
    const float* x   = (const float*)d_in[0];
    const int*   ei  = (const int*)d_in[1];   // [2, E]
    const float* ew  = (const float*)d_in[2];
    const float* W1  = (const float*)d_in[3];
    const float* b1  = (const float*)d_in[4];
    const float* Wmu = (const float*)d_in[5];
    const float* bmu = (const float*)d_in[6];
    const float* Wlv = (const float*)d_in[7];
    const float* blv = (const float*)d_in[8];
    float* outp = (float*)d_out;

    const int n = in_sizes[0] / 128;
    const int E = in_sizes[2];
    const int* src = ei;
    const int* dst = ei + E;
    const int NB = (n + NPB - 1) / NPB;            // bins of 256 nodes (391)

    // workspace layout
    size_t o = 0;
    auto alloc = [&](size_t bytes) { void* p = (char*)d_ws + o; o += (bytes + 511) & ~(size_t)511; return p; };
    int*   bin_cnt  = (int*)alloc((size_t)NB * 4);                 // memset 0
    int2*  rowcnt   = (int2*)alloc((size_t)n * 8);
    float* dinv     = (float*)alloc((size_t)n * 4);
    unsigned long long* csr  = (unsigned long long*)alloc((size_t)E * 8);
    unsigned long long* ebuf = (unsigned long long*)alloc((size_t)NB * CAPE * 8);
    unsigned short* g0 = (unsigned short*)alloc((size_t)n * 64 * 2);   // bf16
    unsigned short* h  = (unsigned short*)alloc((size_t)n * 64 * 2);   // bf16
    unsigned short* g2 = g0;   // gemm2 output reuses g0 (dead after prop1)

    const int gb = (n + 127) / 128;                // gemm blocks (782), 128-row tiles
    const int bb = (E + 4095) / 4096;              // bin blocks (391)

    hipMemsetAsync(bin_cnt, 0, (size_t)NB * 4, stream);
    k_fused1<<<gb + bb, 256, 0, stream>>>(x, W1, g0, src, dst, ew,
                                          bin_cnt, ebuf, n, E, gb, NB);
    k_csr_build<<<NB, 512, 0, stream>>>(ebuf, bin_cnt, rowcnt, dinv, csr, g0, n);
    k_prop<true, false><<<(n + 3) / 4, 256, 0, stream>>>(g0, (const int2*)csr, rowcnt, dinv,
                                                         b1, nullptr, h, n);
    k_gemm2<<<gb, 256, 0, stream>>>(h, Wmu, Wlv, dinv, g2, n);
    k_prop<false, true><<<(n + 3) / 4, 256, 0, stream>>>(g2, (const int2*)csr, rowcnt, dinv,
                                                         bmu, blv, outp, n);
}